// Round 1
// baseline (1724.471 us; speedup 1.0000x reference)
//
#include <hip/hip_runtime.h>
#include <cstddef>

// Swin shifted-window attention, fused per-window kernel (fp32 baseline).
// B=8, H=W=224, E=96, NH=3 (hd=32), WS=7 (N=49), SHIFT=3.
// 8192 windows, one per 256-thread block.

__global__ __launch_bounds__(256, 1)
void swin_attn_kernel(const float* __restrict__ x,
                      const float* __restrict__ w_qkv,
                      const float* __restrict__ b_qkv,
                      const float* __restrict__ w_out,
                      const float* __restrict__ b_out,
                      const float* __restrict__ bias_table,
                      const int* __restrict__ rel_index,
                      float* __restrict__ out)
{
    constexpr int WSZ = 7, N = 49, E = 96, NH = 3, HD = 32, IMG = 224, SHIFT = 3;
    constexpr int XST = 100;   // xs row stride (floats)
    constexpr int WST = 100;   // wb row stride
    constexpr int QST = 292;   // qkv row stride (q|k|v packed: 3*96)
    constexpr int SST = 56;    // scores row stride

    __shared__ float xs[N * XST];     // window input; later attention output (49x96)
    __shared__ float wb[E * WST];     // staged weight chunk (96x96); reused as scores (49x56=2744 <= 9600)
    __shared__ float qkvs[N * QST];   // per-token q|k|v

    float* sc = wb;

    const int tid = threadIdx.x;
    const int blk = blockIdx.x;
    const int b  = blk >> 10;         // batch
    const int wi = (blk >> 5) & 31;   // window row
    const int wj = blk & 31;          // window col

    const int tg = tid >> 5;          // token group 0..7 (7 active: 7 tokens each)
    const int cg = tid & 31;          // lane within group
    const int t0 = tg * 7;

    // ---------------- Phase 0: load shifted window into LDS ----------------
    // shifted-image pixel (r,c) = x[b][(r+3)%224][(c+3)%224]
    for (int idx = tid; idx < N * 24; idx += 256) {
        const int t  = idx / 24, k4 = idx % 24;
        const int r  = (wi * WSZ + t / WSZ + SHIFT) % IMG;
        const int c  = (wj * WSZ + t % WSZ + SHIFT) % IMG;
        const float4 v = *reinterpret_cast<const float4*>(
            x + (((size_t)b * IMG + r) * IMG + c) * E + k4 * 4);
        *reinterpret_cast<float4*>(&xs[t * XST + k4 * 4]) = v;
    }
    __syncthreads();

    // ---------------- Phase 1: QKV projection (3 chunks of 96 out-channels) ----------------
    const float scale = 0.17677669529663688f;   // 1/sqrt(32)
    for (int chunk = 0; chunk < 3; ++chunk) {
        for (int idx = tid; idx < E * 24; idx += 256) {
            const int o = idx / 24, k4 = idx % 24;
            const float4 v = *reinterpret_cast<const float4*>(
                w_qkv + ((size_t)(chunk * E + o)) * E + k4 * 4);
            *reinterpret_cast<float4*>(&wb[o * WST + k4 * 4]) = v;
        }
        __syncthreads();
        if (tg < 7) {
            float acc[7][3];
            #pragma unroll
            for (int i = 0; i < 7; ++i)
                #pragma unroll
                for (int j = 0; j < 3; ++j) acc[i][j] = 0.f;

            for (int k4 = 0; k4 < 24; ++k4) {
                float4 xv[7], wv[3];
                #pragma unroll
                for (int j = 0; j < 3; ++j)
                    wv[j] = *reinterpret_cast<const float4*>(&wb[(cg + 32 * j) * WST + k4 * 4]);
                #pragma unroll
                for (int i = 0; i < 7; ++i)
                    xv[i] = *reinterpret_cast<const float4*>(&xs[(t0 + i) * XST + k4 * 4]);
                #pragma unroll
                for (int i = 0; i < 7; ++i)
                    #pragma unroll
                    for (int j = 0; j < 3; ++j) {
                        acc[i][j] = fmaf(xv[i].x, wv[j].x, acc[i][j]);
                        acc[i][j] = fmaf(xv[i].y, wv[j].y, acc[i][j]);
                        acc[i][j] = fmaf(xv[i].z, wv[j].z, acc[i][j]);
                        acc[i][j] = fmaf(xv[i].w, wv[j].w, acc[i][j]);
                    }
            }
            #pragma unroll
            for (int j = 0; j < 3; ++j) {
                const int o = cg + 32 * j;
                const float bias = b_qkv[chunk * E + o];
                #pragma unroll
                for (int i = 0; i < 7; ++i) {
                    float v = acc[i][j] + bias;
                    if (chunk == 0) v *= scale;    // fold q-scale (incl. bias, as in reference)
                    qkvs[(t0 + i) * QST + chunk * E + o] = v;
                }
            }
        }
        __syncthreads();
    }

    // ---------------- Phase 2: attention per head ----------------
    for (int h = 0; h < NH; ++h) {
        // scores = (q*scale) . k + bias
        if (tg < 7) {
            const int u0 = cg, u1 = cg + 32;
            float a0[7], a1[7];
            #pragma unroll
            for (int i = 0; i < 7; ++i) { a0[i] = 0.f; a1[i] = 0.f; }
            for (int d4 = 0; d4 < 8; ++d4) {
                const int koff = E + h * HD + d4 * 4;
                const float4 kv0 = *reinterpret_cast<const float4*>(&qkvs[u0 * QST + koff]);
                float4 kv1 = make_float4(0.f, 0.f, 0.f, 0.f);
                if (u1 < N) kv1 = *reinterpret_cast<const float4*>(&qkvs[u1 * QST + koff]);
                #pragma unroll
                for (int i = 0; i < 7; ++i) {
                    const float4 qv = *reinterpret_cast<const float4*>(&qkvs[(t0 + i) * QST + h * HD + d4 * 4]);
                    a0[i] = fmaf(qv.x, kv0.x, a0[i]);
                    a0[i] = fmaf(qv.y, kv0.y, a0[i]);
                    a0[i] = fmaf(qv.z, kv0.z, a0[i]);
                    a0[i] = fmaf(qv.w, kv0.w, a0[i]);
                    a1[i] = fmaf(qv.x, kv1.x, a1[i]);
                    a1[i] = fmaf(qv.y, kv1.y, a1[i]);
                    a1[i] = fmaf(qv.z, kv1.z, a1[i]);
                    a1[i] = fmaf(qv.w, kv1.w, a1[i]);
                }
            }
            #pragma unroll
            for (int i = 0; i < 7; ++i) {
                const int t = t0 + i;
                sc[t * SST + u0] = a0[i] + bias_table[rel_index[t * N + u0] * NH + h];
                if (u1 < N)
                    sc[t * SST + u1] = a1[i] + bias_table[rel_index[t * N + u1] * NH + h];
            }
        }
        __syncthreads();

        // softmax over each row (4 lanes per row)
        {
            const int row = tid >> 2, sub = tid & 3;
            if (row < N) {
                float m = -1e30f;
                for (int u = sub; u < N; u += 4) m = fmaxf(m, sc[row * SST + u]);
                m = fmaxf(m, __shfl_xor(m, 1));
                m = fmaxf(m, __shfl_xor(m, 2));
                float s = 0.f;
                for (int u = sub; u < N; u += 4) {
                    const float e = __expf(sc[row * SST + u] - m);
                    sc[row * SST + u] = e;
                    s += e;
                }
                s += __shfl_xor(s, 1);
                s += __shfl_xor(s, 2);
                const float inv = 1.f / s;
                for (int u = sub; u < N; u += 4) sc[row * SST + u] *= inv;
            }
        }
        __syncthreads();

        // PV: attn_out[t][h*32+d] = sum_u attn[t][u] * v[u][h*32+d]
        if (tg < 7) {
            const int d = cg;
            float acc[7];
            #pragma unroll
            for (int i = 0; i < 7; ++i) acc[i] = 0.f;
            for (int u4 = 0; u4 < 12; ++u4) {
                float vv[4];
                #pragma unroll
                for (int uu = 0; uu < 4; ++uu)
                    vv[uu] = qkvs[(u4 * 4 + uu) * QST + 2 * E + h * HD + d];
                #pragma unroll
                for (int i = 0; i < 7; ++i) {
                    const float4 sv = *reinterpret_cast<const float4*>(&sc[(t0 + i) * SST + u4 * 4]);
                    acc[i] = fmaf(sv.x, vv[0], acc[i]);
                    acc[i] = fmaf(sv.y, vv[1], acc[i]);
                    acc[i] = fmaf(sv.z, vv[2], acc[i]);
                    acc[i] = fmaf(sv.w, vv[3], acc[i]);
                }
            }
            const float vlast = qkvs[48 * QST + 2 * E + h * HD + d];
            #pragma unroll
            for (int i = 0; i < 7; ++i) {
                acc[i] = fmaf(sc[(t0 + i) * SST + 48], vlast, acc[i]);
                xs[(t0 + i) * XST + h * HD + d] = acc[i];
            }
        }
        __syncthreads();
    }

    // ---------------- Phase 3: output projection + scattered store ----------------
    for (int idx = tid; idx < E * 24; idx += 256) {
        const int o = idx / 24, k4 = idx % 24;
        const float4 v = *reinterpret_cast<const float4*>(w_out + (size_t)o * E + k4 * 4);
        *reinterpret_cast<float4*>(&wb[o * WST + k4 * 4]) = v;
    }
    __syncthreads();

    if (tg < 7) {
        float acc[7][3];
        #pragma unroll
        for (int i = 0; i < 7; ++i)
            #pragma unroll
            for (int j = 0; j < 3; ++j) acc[i][j] = 0.f;

        for (int k4 = 0; k4 < 24; ++k4) {
            float4 xv[7], wv[3];
            #pragma unroll
            for (int j = 0; j < 3; ++j)
                wv[j] = *reinterpret_cast<const float4*>(&wb[(cg + 32 * j) * WST + k4 * 4]);
            #pragma unroll
            for (int i = 0; i < 7; ++i)
                xv[i] = *reinterpret_cast<const float4*>(&xs[(t0 + i) * XST + k4 * 4]);
            #pragma unroll
            for (int i = 0; i < 7; ++i)
                #pragma unroll
                for (int j = 0; j < 3; ++j) {
                    acc[i][j] = fmaf(xv[i].x, wv[j].x, acc[i][j]);
                    acc[i][j] = fmaf(xv[i].y, wv[j].y, acc[i][j]);
                    acc[i][j] = fmaf(xv[i].z, wv[j].z, acc[i][j]);
                    acc[i][j] = fmaf(xv[i].w, wv[j].w, acc[i][j]);
                }
        }
        #pragma unroll
        for (int i = 0; i < 7; ++i) {
            const int t = t0 + i;
            const int r = (wi * WSZ + t / WSZ + SHIFT) % IMG;
            const int c = (wj * WSZ + t % WSZ + SHIFT) % IMG;
            float* op = out + (((size_t)b * IMG + r) * IMG + c) * E;
            #pragma unroll
            for (int j = 0; j < 3; ++j)
                op[cg + 32 * j] = acc[i][j] + b_out[cg + 32 * j];
        }
    }
}

extern "C" void kernel_launch(void* const* d_in, const int* in_sizes, int n_in,
                              void* d_out, int out_size, void* d_ws, size_t ws_size,
                              hipStream_t stream) {
    const float* x          = (const float*)d_in[0];
    const float* w_qkv      = (const float*)d_in[1];
    const float* b_qkv      = (const float*)d_in[2];
    const float* w_out      = (const float*)d_in[3];
    const float* b_out      = (const float*)d_in[4];
    const float* bias_table = (const float*)d_in[5];
    const int*   rel_index  = (const int*)d_in[6];
    float* outp = (float*)d_out;

    swin_attn_kernel<<<dim3(8192), dim3(256), 0, stream>>>(
        x, w_qkv, b_qkv, w_out, b_out, bias_table, rel_index, outp);
}

// Round 2
// 453.456 us; speedup vs baseline: 3.8030x; 3.8030x over previous
//
#include <hip/hip_runtime.h>
#include <cstddef>

// Swin shifted-window attention, fused per-window MFMA kernel.
// B=8, H=W=224, E=96, NH=3 (hd=32), WS=7 (N=49 -> padded 64), SHIFT=3.
// 8192 windows, one per 256-thread block (4 waves), 2 blocks/CU (74.75 KB LDS).
//
// Precision plan (threshold 1.94e-3, fp32 floor measured 4.9e-4):
//   QKV projection: split-bf16 (x hi/lo in regs, W hi/lo from d_ws) -> ~2^-16 rel
//   scores q*k:     single bf16 x single bf16 (q,k quant ~4e-4 -> score err ~6e-4)
//   P*V:            single bf16
//   out-proj:       A(ao) single bf16, B(w_out) split hi/lo
// Predicted added absmax ~3-5e-4 on top of 4.9e-4 floor.

typedef short s8v __attribute__((ext_vector_type(8)));
typedef float f4v __attribute__((ext_vector_type(4)));

#define MFMA16(A, B, C) __builtin_amdgcn_mfma_f32_16x16x32_bf16((A), (B), (C), 0, 0, 0)

__device__ inline unsigned short f2bf(float f) {
    unsigned u = __builtin_bit_cast(unsigned, f);
    u += 0x7FFFu + ((u >> 16) & 1u);          // round-to-nearest-even
    return (unsigned short)(u >> 16);
}
__device__ inline float bf2f(unsigned short h) {
    unsigned u = ((unsigned)h) << 16;
    return __builtin_bit_cast(float, u);
}

// ---------------- prep: split weights to bf16 hi/lo, expand rel-pos bias ----------------
__global__ void prep_kernel(const float* __restrict__ wqkv, const float* __restrict__ wout,
                            const float* __restrict__ btab, const int* __restrict__ ridx,
                            unsigned short* __restrict__ wqh, unsigned short* __restrict__ wql,
                            unsigned short* __restrict__ woh, unsigned short* __restrict__ wol,
                            float* __restrict__ bmat)
{
    const int i = blockIdx.x * 256 + threadIdx.x;
    if (i < 27648) {                          // w_qkv: 288x96
        const float f = wqkv[i];
        const unsigned short h = f2bf(f);
        wqh[i] = h;
        wql[i] = f2bf(f - bf2f(h));
    } else if (i < 36864) {                   // w_out: 96x96
        const int j = i - 27648;
        const float f = wout[j];
        const unsigned short h = f2bf(f);
        woh[j] = h;
        wol[j] = f2bf(f - bf2f(h));
    } else if (i < 44067) {                   // bias matrix [3][49][49]
        const int j = i - 36864;
        const int hh = j / 2401, r = j - hh * 2401;
        bmat[j] = btab[ridx[r] * 3 + hh];
    }
}

// ---------------- main fused kernel ----------------
__global__ __launch_bounds__(256, 2)
void swin_mfma_kernel(const float* __restrict__ x,
                      const unsigned short* __restrict__ wqh,
                      const unsigned short* __restrict__ wql,
                      const unsigned short* __restrict__ woh,
                      const unsigned short* __restrict__ wol,
                      const float* __restrict__ bqkv,
                      const float* __restrict__ bout,
                      const float* __restrict__ bm,
                      float* __restrict__ out)
{
    // Fragment-linear LDS tiles: addr = frag*512 + lane*8 (+j), 16B/lane -> conflict-free b128.
    // qt/kt: [3 heads][4 tiles] ; vt: [3][2 d-tiles][2 ku] ; aot: [4 m][3 ks] ; pt: [4 m][2 ku]
    __shared__ __attribute__((aligned(16))) unsigned short qt[12 * 512];   // 12288 B
    __shared__ __attribute__((aligned(16))) unsigned short kt[12 * 512];   // 12288 B
    __shared__ __attribute__((aligned(16))) unsigned short vt[12 * 512];   // 12288 B
    __shared__ __attribute__((aligned(16))) unsigned short aot[12 * 512];  // 12288 B
    __shared__ __attribute__((aligned(16))) float sc[64 * 68];             // 17408 B
    __shared__ __attribute__((aligned(16))) unsigned short pt[8 * 512];    // 8192 B
                                                                           // total 74752 B

    const int tid  = threadIdx.x;
    const int wid  = tid >> 6;        // wave 0..3
    const int lane = tid & 63;
    const int l15  = lane & 15;
    const int lg   = lane >> 4;       // 0..3

    const int blk = blockIdx.x;
    const int bb  = blk >> 10;
    const int wi7 = ((blk >> 5) & 31) * 7;
    const int wj7 = (blk & 31) * 7;

    auto pixoff = [&](int t) -> size_t {
        const int tr = t / 7, tc = t % 7;
        int r = wi7 + tr + 3; if (r >= 224) r -= 224;
        int c = wj7 + tc + 3; if (c >= 224) c -= 224;
        return ((size_t)((bb * 224 + r) * 224 + c)) * 96;
    };

    const float SCALE = 0.17677669529663688f;   // 1/sqrt(32)

    // ============ Phase 1: QKV projection (split-bf16 MFMA) ============
    for (int m = 0; m < 4; ++m) {
        const int t = m * 16 + l15;
        s8v ahi[3], alo[3];
        if (t < 49) {
            const float* xrow = x + pixoff(t);
            #pragma unroll
            for (int ks = 0; ks < 3; ++ks) {
                const float4 f0 = *reinterpret_cast<const float4*>(xrow + ks * 32 + lg * 8);
                const float4 f1 = *reinterpret_cast<const float4*>(xrow + ks * 32 + lg * 8 + 4);
                const float fv[8] = {f0.x, f0.y, f0.z, f0.w, f1.x, f1.y, f1.z, f1.w};
                #pragma unroll
                for (int j = 0; j < 8; ++j) {
                    const unsigned short h = f2bf(fv[j]);
                    ahi[ks][j] = (short)h;
                    alo[ks][j] = (short)f2bf(fv[j] - bf2f(h));
                }
            }
        } else {
            #pragma unroll
            for (int ks = 0; ks < 3; ++ks) {
                #pragma unroll
                for (int j = 0; j < 8; ++j) { ahi[ks][j] = 0; alo[ks][j] = 0; }
            }
        }
        for (int n = wid; n < 18; n += 4) {
            const unsigned short* bhp = wqh + (size_t)(n * 16 + l15) * 96 + lg * 8;
            const unsigned short* blp = wql + (size_t)(n * 16 + l15) * 96 + lg * 8;
            f4v acc = {0.f, 0.f, 0.f, 0.f};
            #pragma unroll
            for (int ks = 0; ks < 3; ++ks) {
                const s8v bh = *reinterpret_cast<const s8v*>(bhp + ks * 32);
                const s8v bl = *reinterpret_cast<const s8v*>(blp + ks * 32);
                acc = MFMA16(ahi[ks], bh, acc);
                acc = MFMA16(ahi[ks], bl, acc);
                acc = MFMA16(alo[ks], bh, acc);
            }
            const int oc = n * 16 + l15;
            const float bias = bqkv[oc];
            if (n < 12) {       // q or k -> row-fragment layout [h][m]
                const int c  = (n < 6) ? oc : (oc - 96);
                const int hh = c >> 5, d = c & 31;
                unsigned short* dst = (n < 6) ? qt : kt;
                const int base = (hh * 4 + m) * 512 + 16 * (d >> 3) * 8 + (d & 7);
                #pragma unroll
                for (int i = 0; i < 4; ++i) {
                    float v = acc[i] + bias;
                    if (n < 6) v *= SCALE;
                    dst[base + (lg * 4 + i) * 8] = f2bf(v);
                }
            } else {            // v -> B-operand fragment layout [h][ndt][ku]
                const int c  = oc - 192;
                const int hh = c >> 5, dd = c & 31, ndt = dd >> 4, dcol = dd & 15;
                #pragma unroll
                for (int i = 0; i < 4; ++i) {
                    const float v = acc[i] + bias;
                    const int u = m * 16 + lg * 4 + i;
                    vt[((hh * 2 + ndt) * 2 + (u >> 5)) * 512 +
                       (dcol + 16 * ((u & 31) >> 3)) * 8 + (u & 7)] = f2bf(v);
                }
            }
        }
    }
    __syncthreads();

    // ============ Phase 2: per-head attention ============
    for (int h = 0; h < 3; ++h) {
        // ---- scores: D[t][u] = sum_d q[t][d] k[u][d] (wave wid owns u-tile wid) ----
        {
            const s8v kb = *reinterpret_cast<const s8v*>(&kt[(h * 4 + wid) * 512 + lane * 8]);
            #pragma unroll
            for (int m = 0; m < 4; ++m) {
                const s8v qa = *reinterpret_cast<const s8v*>(&qt[(h * 4 + m) * 512 + lane * 8]);
                f4v s = {0.f, 0.f, 0.f, 0.f};
                s = MFMA16(qa, kb, s);
                #pragma unroll
                for (int i = 0; i < 4; ++i)
                    sc[(m * 16 + lg * 4 + i) * 68 + wid * 16 + l15] = s[i];
            }
        }
        __syncthreads();
        // ---- softmax (+rel-pos bias), write P as bf16 fragments ----
        {
            const int t = tid >> 2, sub = tid & 3;
            if (t < 49) {
                const float* bmrow = bm + h * 2401 + t * 49;
                float vals[16];
                float mx = -1e30f;
                #pragma unroll
                for (int kk = 0; kk < 16; ++kk) {
                    const int u = sub + kk * 4;
                    float v = -1e30f;
                    if (u < 49) v = sc[t * 68 + u] + bmrow[u];
                    vals[kk] = v;
                    mx = fmaxf(mx, v);
                }
                mx = fmaxf(mx, __shfl_xor(mx, 1));
                mx = fmaxf(mx, __shfl_xor(mx, 2));
                float sm = 0.f;
                #pragma unroll
                for (int kk = 0; kk < 16; ++kk) {
                    const int u = sub + kk * 4;
                    float e = 0.f;
                    if (u < 49) e = __expf(vals[kk] - mx);
                    vals[kk] = e;
                    sm += e;
                }
                sm += __shfl_xor(sm, 1);
                sm += __shfl_xor(sm, 2);
                const float inv = 1.f / sm;
                #pragma unroll
                for (int kk = 0; kk < 16; ++kk) {
                    const int u = sub + kk * 4;   // covers all u in [0,64) with u%4==sub
                    const float p = (u < 49) ? vals[kk] * inv : 0.f;
                    pt[((t >> 4) * 2 + (u >> 5)) * 512 +
                       ((t & 15) + 16 * ((u & 31) >> 3)) * 8 + (u & 7)] = f2bf(p);
                }
            }
        }
        __syncthreads();
        // ---- PV: D[t][d] = sum_u P[t][u] V[u][d] (wave wid owns m-tile wid) ----
        {
            const int m = wid;
            #pragma unroll
            for (int nd = 0; nd < 2; ++nd) {
                f4v acc = {0.f, 0.f, 0.f, 0.f};
                #pragma unroll
                for (int ku = 0; ku < 2; ++ku) {
                    const s8v pa = *reinterpret_cast<const s8v*>(&pt[(m * 2 + ku) * 512 + lane * 8]);
                    const s8v vb = *reinterpret_cast<const s8v*>(&vt[((h * 2 + nd) * 2 + ku) * 512 + lane * 8]);
                    acc = MFMA16(pa, vb, acc);
                }
                const int ch = h * 32 + nd * 16 + l15;
                #pragma unroll
                for (int i = 0; i < 4; ++i) {
                    const int tt = m * 16 + lg * 4 + i;
                    aot[(m * 3 + h) * 512 +
                        ((tt & 15) + 16 * ((ch & 31) >> 3)) * 8 + (ch & 7)] = f2bf(acc[i]);
                }
            }
        }
        // no trailing sync needed: next head's post-scores barrier orders pt reuse
    }
    __syncthreads();

    // ============ Phase 3: output projection + scattered store ============
    #pragma unroll
    for (int q = 0; q < 6; ++q) {
        const int p = wid * 6 + q;            // 24 (n,m) pairs, 6 per wave
        const int n = p >> 2, m = p & 3;
        const unsigned short* bhp = woh + (size_t)(n * 16 + l15) * 96 + lg * 8;
        const unsigned short* blp = wol + (size_t)(n * 16 + l15) * 96 + lg * 8;
        f4v acc = {0.f, 0.f, 0.f, 0.f};
        #pragma unroll
        for (int ks = 0; ks < 3; ++ks) {
            const s8v aa = *reinterpret_cast<const s8v*>(&aot[(m * 3 + ks) * 512 + lane * 8]);
            const s8v bh = *reinterpret_cast<const s8v*>(bhp + ks * 32);
            const s8v bl = *reinterpret_cast<const s8v*>(blp + ks * 32);
            acc = MFMA16(aa, bh, acc);
            acc = MFMA16(aa, bl, acc);
        }
        const float bo = bout[n * 16 + l15];
        #pragma unroll
        for (int i = 0; i < 4; ++i) {
            const int tt = m * 16 + lg * 4 + i;
            if (tt < 49)
                out[pixoff(tt) + n * 16 + l15] = acc[i] + bo;
        }
    }
}

extern "C" void kernel_launch(void* const* d_in, const int* in_sizes, int n_in,
                              void* d_out, int out_size, void* d_ws, size_t ws_size,
                              hipStream_t stream) {
    const float* x          = (const float*)d_in[0];
    const float* w_qkv      = (const float*)d_in[1];
    const float* b_qkv      = (const float*)d_in[2];
    const float* w_out      = (const float*)d_in[3];
    const float* b_out      = (const float*)d_in[4];
    const float* bias_table = (const float*)d_in[5];
    const int*   rel_index  = (const int*)d_in[6];
    float* outp = (float*)d_out;

    // d_ws layout (176268 B total):
    //   wq_hi[27648]u16 | wq_lo[27648]u16 | wo_hi[9216]u16 | wo_lo[9216]u16 | bias[7203]f32
    unsigned short* wqh = (unsigned short*)d_ws;
    unsigned short* wql = wqh + 27648;
    unsigned short* woh = wql + 27648;
    unsigned short* wol = woh + 9216;
    float* bmat = (float*)((char*)d_ws + 147456);

    prep_kernel<<<dim3(173), dim3(256), 0, stream>>>(
        w_qkv, w_out, bias_table, rel_index, wqh, wql, woh, wol, bmat);
    swin_mfma_kernel<<<dim3(8192), dim3(256), 0, stream>>>(
        x, wqh, wql, woh, wol, b_qkv, b_out, bmat, outp);
}

// Round 3
// 229.123 us; speedup vs baseline: 7.5264x; 1.9791x over previous
//
#include <hip/hip_runtime.h>
#include <cstddef>

// Swin shifted-window attention, fused per-window MFMA kernel, fp16 single-pass.
// B=8, H=W=224, E=96, NH=3 (hd=32), WS=7 (N=49 -> padded 64), SHIFT=3.
// 8192 windows, one per 512-thread block (8 waves); LDS 52.3KB -> 3 blocks/CU.
// 4 barriers total: [qkv] [scores all heads] [softmax->P frags] [PV->ao] phase3.

typedef _Float16 half8 __attribute__((ext_vector_type(8)));
typedef float f4v __attribute__((ext_vector_type(4)));
typedef unsigned short u16;
typedef unsigned int u32;

#define MFMA(A, B, C) __builtin_amdgcn_mfma_f32_16x16x32_f16((A), (B), (C), 0, 0, 0)

__device__ inline u16 f16b(float f) { return __builtin_bit_cast(u16, (_Float16)f); }
__device__ inline u32 pk2(float a, float b) {
    return (u32)__builtin_bit_cast(u16, (_Float16)a) |
           ((u32)__builtin_bit_cast(u16, (_Float16)b) << 16);
}

// ---- prep: weights -> f16, bias table -> dense padded [3][49][64] f32 ----
__global__ void prep_kernel(const float* __restrict__ wqkv, const float* __restrict__ wout,
                            const float* __restrict__ btab, const int* __restrict__ ridx,
                            u16* __restrict__ wq16, u16* __restrict__ wo16,
                            float* __restrict__ bmat)
{
    const int i = blockIdx.x * 256 + threadIdx.x;
    if (i < 27648) {
        wq16[i] = f16b(wqkv[i]);
    } else if (i < 36864) {
        wo16[i - 27648] = f16b(wout[i - 27648]);
    } else if (i < 36864 + 9408) {
        const int j = i - 36864;
        const int h = j / 3136, rem = j - h * 3136;
        const int r = rem >> 6, u = rem & 63;
        bmat[j] = (u < 49) ? btab[ridx[r * 49 + u] * 3 + h] : 0.f;
    }
}

// ---- main fused kernel ----
__global__ __launch_bounds__(512, 6)
void swin_kernel(const float* __restrict__ x,
                 const u16* __restrict__ wq16,
                 const u16* __restrict__ wo16,
                 const float* __restrict__ bqkv,
                 const float* __restrict__ bout,
                 const float* __restrict__ bm,
                 float* __restrict__ out)
{
    // LDS map (53584 B):
    //   [0,24576)      qt(12 frags)+kt(12 frags); reused as pt[3][8 frags] after scores
    //   [24576,36864)  vt (12 frags)
    //   [36864,53328)  sc f16 [3][49][56]; reused as aot (12 frags) during PV
    //   [53328,53584)  pix[64] u32
    __shared__ __attribute__((aligned(16))) char smem[53584];
    u16* qt  = (u16*)smem;
    u16* kt  = (u16*)(smem + 12288);
    u16* pt  = (u16*)smem;
    u16* vt  = (u16*)(smem + 24576);
    u16* sc  = (u16*)(smem + 36864);
    u16* aot = (u16*)(smem + 36864);
    u32* pix = (u32*)(smem + 53328);

    const int tid  = threadIdx.x;
    const int w    = tid >> 6;
    const int lane = tid & 63;
    const int l15  = lane & 15;
    const int lg   = lane >> 4;

    const int blk = blockIdx.x;
    const int bb  = blk >> 10;
    const int wi7 = ((blk >> 5) & 31) * 7;
    const int wj7 = (blk & 31) * 7;

    if (tid < 64) {
        const int t = tid;
        const int tr = t / 7, tc = t - tr * 7;
        int r = wi7 + tr + 3; if (r >= 224) r -= 224;
        int c = wj7 + tc + 3; if (c >= 224) c -= 224;
        pix[t] = (u32)(((bb * 224 + r) * 224 + c) * 96);
    }

    // ============ Phase 1: QKV projection (fp16 MFMA) ============
    {
        const int mh2 = (w >> 2) * 2;       // this wave handles m-tiles mh2, mh2+1
        half8 a[2][3];
        #pragma unroll
        for (int mi = 0; mi < 2; ++mi) {
            const int t = (mh2 + mi) * 16 + l15;
            if (t < 49) {
                const int tr = t / 7, tc = t - tr * 7;
                int r = wi7 + tr + 3; if (r >= 224) r -= 224;
                int c = wj7 + tc + 3; if (c >= 224) c -= 224;
                const float* xrow = x + ((size_t)((bb * 224 + r) * 224 + c)) * 96 + lg * 8;
                #pragma unroll
                for (int ks = 0; ks < 3; ++ks) {
                    const float4 f0 = *(const float4*)(xrow + ks * 32);
                    const float4 f1 = *(const float4*)(xrow + ks * 32 + 4);
                    half8 hv;
                    hv[0] = (_Float16)f0.x; hv[1] = (_Float16)f0.y;
                    hv[2] = (_Float16)f0.z; hv[3] = (_Float16)f0.w;
                    hv[4] = (_Float16)f1.x; hv[5] = (_Float16)f1.y;
                    hv[6] = (_Float16)f1.z; hv[7] = (_Float16)f1.w;
                    a[mi][ks] = hv;
                }
            } else {
                const half8 hz = {0, 0, 0, 0, 0, 0, 0, 0};
                a[mi][0] = hz; a[mi][1] = hz; a[mi][2] = hz;
            }
        }
        const int nw = w & 3;
        for (int n = nw; n < 18; n += 4) {
            const u16* bp = wq16 + (size_t)(n * 16 + l15) * 96 + lg * 8;
            const half8 b0 = *(const half8*)(bp);
            const half8 b1 = *(const half8*)(bp + 32);
            const half8 b2 = *(const half8*)(bp + 64);
            f4v acc0 = {0.f, 0.f, 0.f, 0.f}, acc1 = {0.f, 0.f, 0.f, 0.f};
            acc0 = MFMA(a[0][0], b0, acc0);
            acc0 = MFMA(a[0][1], b1, acc0);
            acc0 = MFMA(a[0][2], b2, acc0);
            acc1 = MFMA(a[1][0], b0, acc1);
            acc1 = MFMA(a[1][1], b1, acc1);
            acc1 = MFMA(a[1][2], b2, acc1);
            const int oc = n * 16 + l15;
            const float bias = bqkv[oc];
            if (n < 12) {                      // q (n<6) or k
                const int c  = (n < 6) ? oc : oc - 96;
                const int hh = c >> 5, d = c & 31;
                u16* dst = (n < 6) ? qt : kt;
                const float mul = (n < 6) ? 0.17677669529663688f : 1.0f;
                const int eb = ((d >> 3) * 16) * 8 + (d & 7);
                #pragma unroll
                for (int mi = 0; mi < 2; ++mi) {
                    const int mt = mh2 + mi;
                    const int fb = (hh * 4 + mt) * 512 + eb;
                    #pragma unroll
                    for (int i = 0; i < 4; ++i) {
                        const float v = ((mi ? acc1[i] : acc0[i]) + bias) * mul;
                        dst[fb + (lg * 4 + i) * 8] = f16b(v);
                    }
                }
            } else {                           // v -> B-operand fragments
                const int c  = oc - 192;
                const int hh = c >> 5, ndt = (c >> 4) & 1, dcol = c & 15;
                #pragma unroll
                for (int mi = 0; mi < 2; ++mi) {
                    const int mt = mh2 + mi;
                    #pragma unroll
                    for (int i = 0; i < 4; ++i) {
                        const int u = mt * 16 + lg * 4 + i;
                        const float v = (mi ? acc1[i] : acc0[i]) + bias;
                        vt[((hh * 2 + ndt) * 2 + (u >> 5)) * 512 +
                           (((u & 31) >> 3) * 16 + dcol) * 8 + (u & 7)] = f16b(v);
                    }
                }
            }
        }
    }
    __syncthreads();

    // ============ Phase 2a: scores, all heads ============
    {
        const int ut = w & 3;
        const int pbase = (w >> 2) * 6;
        const int u = ut * 16 + l15;
        const bool colok = u < 56;
        #pragma unroll
        for (int q6 = 0; q6 < 6; ++q6) {
            const int p = pbase + q6, h = p >> 2, m = p & 3;
            const half8 qa = *(const half8*)&qt[(h * 4 + m) * 512 + lane * 8];
            const half8 kb = *(const half8*)&kt[(h * 4 + ut) * 512 + lane * 8];
            f4v z = {0.f, 0.f, 0.f, 0.f};
            const f4v s = MFMA(qa, kb, z);
            #pragma unroll
            for (int i = 0; i < 4; ++i) {
                const int t = m * 16 + lg * 4 + i;
                if (t < 49 && colok)
                    sc[(h * 49 + t) * 56 + u] = f16b(s[i]);
            }
        }
    }
    __syncthreads();

    // ============ Phase 2b: softmax all rows -> P fragments (over dead qt/kt) ============
    {
        const int sub = tid & 3;
        const int u0 = sub * 16;
        for (int rr = tid >> 2; rr < 147; rr += 128) {
            const int h = (rr >= 98) ? 2 : (rr >= 49 ? 1 : 0);
            const int t = rr - h * 49;
            const u16* srow = sc + (h * 49 + t) * 56 + u0;
            const float* brow = bm + (h * 49 + t) * 64 + u0;
            float vals[16];
            float mx = -1e30f;
            #pragma unroll
            for (int g = 0; g < 2; ++g) {
                const half8 sv = *(const half8*)(srow + g * 8);
                const float4 bv0 = *(const float4*)(brow + g * 8);
                const float4 bv1 = *(const float4*)(brow + g * 8 + 4);
                const float bArr[8] = {bv0.x, bv0.y, bv0.z, bv0.w, bv1.x, bv1.y, bv1.z, bv1.w};
                #pragma unroll
                for (int j = 0; j < 8; ++j) {
                    const int u = u0 + g * 8 + j;
                    const float v = (u < 49) ? ((float)sv[j] + bArr[j]) : -1e30f;
                    vals[g * 8 + j] = v;
                    mx = fmaxf(mx, v);
                }
            }
            mx = fmaxf(mx, __shfl_xor(mx, 1));
            mx = fmaxf(mx, __shfl_xor(mx, 2));
            float sm = 0.f;
            #pragma unroll
            for (int j = 0; j < 16; ++j) { const float e = __expf(vals[j] - mx); vals[j] = e; sm += e; }
            sm += __shfl_xor(sm, 1);
            sm += __shfl_xor(sm, 2);
            const float inv = 1.f / sm;
            #pragma unroll
            for (int j = 0; j < 16; ++j) vals[j] *= inv;
            const int base = h * 4096 + ((t >> 4) * 2 + (u0 >> 5)) * 512 +
                             ((t & 15) + 16 * ((u0 & 31) >> 3)) * 8;
            uint4 w0, w1;
            w0.x = pk2(vals[0],  vals[1]);  w0.y = pk2(vals[2],  vals[3]);
            w0.z = pk2(vals[4],  vals[5]);  w0.w = pk2(vals[6],  vals[7]);
            w1.x = pk2(vals[8],  vals[9]);  w1.y = pk2(vals[10], vals[11]);
            w1.z = pk2(vals[12], vals[13]); w1.w = pk2(vals[14], vals[15]);
            *(uint4*)&pt[base] = w0;
            *(uint4*)&pt[base + 128] = w1;
        }
    }
    __syncthreads();

    // ============ Phase 2c: PV, all heads -> ao fragments (over dead sc) ============
    {
        const int nd = (w >> 2) & 1;
        const int m  = w & 3;
        const int kl = nd * 16 + l15;
        const int abase = ((kl >> 3) * 16) * 8 + (kl & 7);
        #pragma unroll
        for (int h = 0; h < 3; ++h) {
            f4v acc = {0.f, 0.f, 0.f, 0.f};
            #pragma unroll
            for (int ku = 0; ku < 2; ++ku) {
                const half8 pa = *(const half8*)&pt[h * 4096 + (m * 2 + ku) * 512 + lane * 8];
                const half8 vb = *(const half8*)&vt[((h * 2 + nd) * 2 + ku) * 512 + lane * 8];
                acc = MFMA(pa, vb, acc);
            }
            const int fb = (m * 3 + h) * 512 + abase;
            #pragma unroll
            for (int i = 0; i < 4; ++i)
                aot[fb + (lg * 4 + i) * 8] = f16b(acc[i]);
        }
    }
    __syncthreads();

    // ============ Phase 3: output projection + scattered store ============
    {
        #pragma unroll
        for (int q3 = 0; q3 < 3; ++q3) {
            const int p = q3 * 8 + w;
            const int n = p >> 2, m = p & 3;
            const u16* bp = wo16 + (size_t)(n * 16 + l15) * 96 + lg * 8;
            const half8 b0 = *(const half8*)(bp);
            const half8 b1 = *(const half8*)(bp + 32);
            const half8 b2 = *(const half8*)(bp + 64);
            f4v acc = {0.f, 0.f, 0.f, 0.f};
            acc = MFMA(*(const half8*)&aot[(m * 3 + 0) * 512 + lane * 8], b0, acc);
            acc = MFMA(*(const half8*)&aot[(m * 3 + 1) * 512 + lane * 8], b1, acc);
            acc = MFMA(*(const half8*)&aot[(m * 3 + 2) * 512 + lane * 8], b2, acc);
            const float bo = bout[n * 16 + l15];
            #pragma unroll
            for (int i = 0; i < 4; ++i) {
                const int t = m * 16 + lg * 4 + i;
                if (t < 49)
                    out[(size_t)pix[t] + n * 16 + l15] = acc[i] + bo;
            }
        }
    }
}

extern "C" void kernel_launch(void* const* d_in, const int* in_sizes, int n_in,
                              void* d_out, int out_size, void* d_ws, size_t ws_size,
                              hipStream_t stream) {
    const float* x          = (const float*)d_in[0];
    const float* w_qkv      = (const float*)d_in[1];
    const float* b_qkv      = (const float*)d_in[2];
    const float* w_out      = (const float*)d_in[3];
    const float* b_out      = (const float*)d_in[4];
    const float* bias_table = (const float*)d_in[5];
    const int*   rel_index  = (const int*)d_in[6];
    float* outp = (float*)d_out;

    // d_ws: wq16[27648]u16 | wo16[9216]u16 | bmat[3*49*64]f32  (111360 B total)
    u16* wq16 = (u16*)d_ws;
    u16* wo16 = wq16 + 27648;
    float* bmat = (float*)((char*)d_ws + 73728);

    prep_kernel<<<dim3(181), dim3(256), 0, stream>>>(
        w_qkv, w_out, bias_table, rel_index, wq16, wo16, bmat);
    swin_kernel<<<dim3(8192), dim3(512), 0, stream>>>(
        x, wq16, wo16, b_qkv, b_out, bmat, outp);
}

// Round 5
// 201.688 us; speedup vs baseline: 8.5502x; 1.1360x over previous
//
#include <hip/hip_runtime.h>
#include <cstddef>

// Swin shifted-window attention, fused per-window MFMA kernel, fp16, v5.
// v4 + fix: softmax row spans lanes {l15, l15+16, l15+32, l15+48} -> butterfly
// reduce (shfl_xor 16/32) for max and sum. Everything else identical to v4.
// B=8, H=W=224, E=96, NH=3 (hd=32), WS=7 (N=49 -> padded 64), SHIFT=3.
// 8192 windows, one per 256-thread block (4 waves, wave = one 16-token m-tile).
//   - S^T = K*Q (swapped MFMA) -> score row in 4 lanes, softmax via 4 shuffles
//   - zero barriers inside attention (all LDS traffic wave-local, DS pipe in-order)
//   - 2 barriers total; LDS = 40960 B exactly -> 4 blocks/CU
//   - bank-swizzled fragment LDS: unit = ((l15 ^ 2kg ^ ((l15&8)>>1))&15)+16kg
//   - transposed out-proj (Wo * O^T) -> float4 global stores

typedef _Float16 half8 __attribute__((ext_vector_type(8)));
typedef float f4v __attribute__((ext_vector_type(4)));
typedef unsigned short u16;
typedef unsigned int u32;

#define MFMA(A, B, C) __builtin_amdgcn_mfma_f32_16x16x32_f16((A), (B), (C), 0, 0, 0)

__device__ inline u16 f16b(float f) { return __builtin_bit_cast(u16, (_Float16)f); }
__device__ inline u32 pkrtz(float a, float b) {
    return __builtin_bit_cast(u32, __builtin_amdgcn_cvt_pkrtz(a, b));
}
// fragment-LDS unit swizzle: byte = frag*1024 + unit*16 + elem*2
__device__ inline int SWU(int a, int kg) {
    return (((a ^ (kg << 1) ^ ((a & 8) >> 1)) & 15) | (kg << 4));
}

// ---- prep: weights -> f16, bias table -> dense padded [3][64][64] f32 ----
__global__ void prep_kernel(const float* __restrict__ wqkv, const float* __restrict__ wout,
                            const float* __restrict__ btab, const int* __restrict__ ridx,
                            u16* __restrict__ wq16, u16* __restrict__ wo16,
                            float* __restrict__ bmat)
{
    const int i = blockIdx.x * 256 + threadIdx.x;
    if (i < 27648) {
        wq16[i] = f16b(wqkv[i]);
    } else if (i < 36864) {
        wo16[i - 27648] = f16b(wout[i - 27648]);
    } else if (i < 36864 + 12288) {
        const int j = i - 36864;
        const int h = j >> 12, rem = j & 4095;
        const int r = rem >> 6, u = rem & 63;
        bmat[j] = (r < 49 && u < 49) ? btab[ridx[r * 49 + u] * 3 + h] : 0.f;
    }
}

// ---- main fused kernel ----
__global__ __launch_bounds__(256, 4)
void swin_kernel(const float* __restrict__ x,
                 const u16* __restrict__ wq16,
                 const u16* __restrict__ wo16,
                 const float* __restrict__ bqkv,
                 const float* __restrict__ bout,
                 const float* __restrict__ bm,
                 float* __restrict__ out)
{
    // LDS map (40960 B exactly -> 4 blocks/CU):
    //   QT [0,12288)      qt frag(h*4+m); reused per head as pt-ku0[m], then aot(h*4+m)
    //   KT [12288,24576)  kt frag(h*4+ut)
    //   VT [24576,36864)  vt frag((h*2+nd)*2+ku)
    //   PL [36864,40960)  pt-ku1, 1KB per wave
    __shared__ __attribute__((aligned(16))) char smem[40960];
    constexpr int QT = 0, KT = 12288, VT = 24576, PL = 36864;

    const int tid  = threadIdx.x;
    const int w    = tid >> 6;        // wave 0..3 = m-tile
    const int lane = tid & 63;
    const int l15  = lane & 15;
    const int lg   = lane >> 4;       // 0..3

    const int blk = blockIdx.x;
    const int bb  = blk >> 10;
    const int wi7 = ((blk >> 5) & 31) * 7;
    const int wj7 = (blk & 31) * 7;

    const float SCALE = 0.17677669529663688f;   // 1/sqrt(32)
    const int swbase = SWU(l15, lg) * 16;       // common read offset

    // ============ Phase 1: QKV projection ============
    // A-frags for all 4 m-tiles in registers (row t = m*16+l15, k = ks*32+lg*8+j)
    half8 xa[4][3];
    #pragma unroll
    for (int m = 0; m < 4; ++m) {
        const int t = m * 16 + l15;
        if (t < 49) {
            const int tr = t / 7, tc = t - tr * 7;
            int r = wi7 + tr + 3; if (r >= 224) r -= 224;
            int c = wj7 + tc + 3; if (c >= 224) c -= 224;
            const float* xrow = x + ((size_t)((bb * 224 + r) * 224 + c)) * 96 + lg * 8;
            #pragma unroll
            for (int ks = 0; ks < 3; ++ks) {
                const float4 f0 = *(const float4*)(xrow + ks * 32);
                const float4 f1 = *(const float4*)(xrow + ks * 32 + 4);
                uint4 pk;
                pk.x = pkrtz(f0.x, f0.y); pk.y = pkrtz(f0.z, f0.w);
                pk.z = pkrtz(f1.x, f1.y); pk.w = pkrtz(f1.z, f1.w);
                xa[m][ks] = __builtin_bit_cast(half8, pk);
            }
        } else {
            const uint4 z = {0, 0, 0, 0};
            xa[m][0] = xa[m][1] = xa[m][2] = __builtin_bit_cast(half8, z);
        }
    }

    {
        const int sw1 = ((lg >> 1) & 1) * 4;    // ((a&8)>>1) for a = lg*4+i, i<4
        half8 bcur[3], bnxt[3];
        int n = w;
        {
            const u16* bp = wq16 + (size_t)(n * 16 + l15) * 96 + lg * 8;
            bcur[0] = *(const half8*)(bp);
            bcur[1] = *(const half8*)(bp + 32);
            bcur[2] = *(const half8*)(bp + 64);
        }
        while (true) {
            const int n2 = n + 4;
            if (n2 < 18) {
                const u16* bp = wq16 + (size_t)(n2 * 16 + l15) * 96 + lg * 8;
                bnxt[0] = *(const half8*)(bp);
                bnxt[1] = *(const half8*)(bp + 32);
                bnxt[2] = *(const half8*)(bp + 64);
            }
            f4v acc[4];
            #pragma unroll
            for (int m = 0; m < 4; ++m) {
                f4v a = {0.f, 0.f, 0.f, 0.f};
                a = MFMA(xa[m][0], bcur[0], a);
                a = MFMA(xa[m][1], bcur[1], a);
                a = MFMA(xa[m][2], bcur[2], a);
                acc[m] = a;
            }
            const int oc = n * 16 + l15;
            const float bias = bqkv[oc];
            if (n < 12) {                       // q (n<6) or k
                const int c  = (n < 6) ? oc : oc - 96;
                const int hh = c >> 5, d = c & 31;
                const int kg = d >> 3, el = d & 7;
                const float mul = (n < 6) ? SCALE : 1.0f;
                char* reg0 = smem + ((n < 6) ? QT : KT) + (hh * 4) * 1024 + el * 2;
                const int xr = (kg << 1) ^ sw1;
                #pragma unroll
                for (int m = 0; m < 4; ++m) {
                    #pragma unroll
                    for (int i = 0; i < 4; ++i) {
                        const float v = (acc[m][i] + bias) * mul;
                        const int unit = (((lg * 4 + i) ^ xr) & 15) | (kg << 4);
                        *(u16*)(reg0 + m * 1024 + unit * 16) = f16b(v);
                    }
                }
            } else {                            // v -> vt B-frags (outer d, k u)
                const int c  = oc - 192;
                const int hh = c >> 5, nd = (c >> 4) & 1;
                const int elb = (lg & 1) * 4;
                #pragma unroll
                for (int m = 0; m < 4; ++m) {
                    const int ku = m >> 1;
                    const int kg = (m & 1) * 2 + (lg >> 1);
                    uint2 pv;
                    pv.x = pkrtz(acc[m][0] + bias, acc[m][1] + bias);
                    pv.y = pkrtz(acc[m][2] + bias, acc[m][3] + bias);
                    *(uint2*)(smem + VT + ((hh * 2 + nd) * 2 + ku) * 1024 +
                              SWU(l15, kg) * 16 + elb * 2) = pv;
                }
            }
            if (n2 >= 18) break;
            bcur[0] = bnxt[0]; bcur[1] = bnxt[1]; bcur[2] = bnxt[2];
            n = n2;
        }
    }
    __syncthreads();

    // ============ Phase 2: attention, zero barriers ============
    {
        const int t = w * 16 + l15;
        const int elb2 = ((lg & 1) * 4) * 2;
        for (int h = 0; h < 3; ++h) {
            const int qfr = QT + (h * 4 + w) * 1024;
            const half8 qa = *(const half8*)(smem + qfr + swbase);
            f4v s[4];
            #pragma unroll
            for (int ut = 0; ut < 4; ++ut) {
                const half8 kb = *(const half8*)(smem + KT + (h * 4 + ut) * 1024 + swbase);
                f4v z = {0.f, 0.f, 0.f, 0.f};
                s[ut] = MFMA(kb, qa, z);        // D[u-rows][t-cols]
            }
            // + relative position bias (dense padded [3][64][64])
            const float* bp = bm + h * 4096 + t * 64 + lg * 4;
            #pragma unroll
            for (int ut = 0; ut < 4; ++ut) {
                const float4 bv = *(const float4*)(bp + ut * 16);
                s[ut][0] += bv.x; s[ut][1] += bv.y; s[ut][2] += bv.z; s[ut][3] += bv.w;
            }
            // mask u >= 49 (ut=3 covers u=48..63: only u=48 i.e. lg==0,i==0 valid)
            s[3][1] = -1e30f; s[3][2] = -1e30f; s[3][3] = -1e30f;
            if (lg) s[3][0] = -1e30f;
            // softmax over row t: 16 values/lane x 4 lanes (lg) -> butterfly over lg
            float mx = -1e30f;
            #pragma unroll
            for (int ut = 0; ut < 4; ++ut)
                #pragma unroll
                for (int i = 0; i < 4; ++i) mx = fmaxf(mx, s[ut][i]);
            mx = fmaxf(mx, __shfl_xor(mx, 16));
            mx = fmaxf(mx, __shfl_xor(mx, 32));
            float sm = 0.f;
            #pragma unroll
            for (int ut = 0; ut < 4; ++ut)
                #pragma unroll
                for (int i = 0; i < 4; ++i) { const float e = __expf(s[ut][i] - mx); s[ut][i] = e; sm += e; }
            sm += __shfl_xor(sm, 16);
            sm += __shfl_xor(sm, 32);
            const float inv = 1.f / sm;
            // P -> pt fragments (ku0 over qt[h,w], ku1 in pool), b64 swizzled writes
            #pragma unroll
            for (int ut = 0; ut < 4; ++ut) {
                uint2 pv;
                pv.x = pkrtz(s[ut][0] * inv, s[ut][1] * inv);
                pv.y = pkrtz(s[ut][2] * inv, s[ut][3] * inv);
                const int kg = (ut & 1) * 2 + (lg >> 1);
                const int base = (ut < 2) ? qfr : (PL + w * 1024);
                *(uint2*)(smem + base + SWU(l15, kg) * 16 + elb2) = pv;
            }
            // PV (reads are wave-local; DS pipe in-order => no barrier)
            const half8 p0 = *(const half8*)(smem + qfr + swbase);
            const half8 p1 = *(const half8*)(smem + PL + w * 1024 + swbase);
            #pragma unroll
            for (int nd = 0; nd < 2; ++nd) {
                f4v o = {0.f, 0.f, 0.f, 0.f};
                o = MFMA(*(const half8*)(smem + VT + ((h * 2 + nd) * 2 + 0) * 1024 + swbase), p0, o);
                o = MFMA(*(const half8*)(smem + VT + ((h * 2 + nd) * 2 + 1) * 1024 + swbase), p1, o);
                // O^T -> aot B-frag (over qt[h,w] region, after p0/p1 consumed)
                uint2 ov;
                ov.x = pkrtz(o[0], o[1]);
                ov.y = pkrtz(o[2], o[3]);
                const int kg = nd * 2 + (lg >> 1);
                *(uint2*)(smem + qfr + SWU(l15, kg) * 16 + elb2) = ov;
            }
        }
    }
    __syncthreads();

    // ============ Phase 3: transposed out-proj (Wo * O^T) + float4 stores ============
    {
        #pragma unroll
        for (int q = 0; q < 6; ++q) {
            const int p = w * 6 + q;
            const int nn = p >> 2, m = p & 3;
            f4v acc = {0.f, 0.f, 0.f, 0.f};
            #pragma unroll
            for (int ks = 0; ks < 3; ++ks) {
                const half8 wa = *(const half8*)(wo16 + (size_t)(nn * 16 + l15) * 96 + ks * 32 + lg * 8);
                const half8 ob = *(const half8*)(smem + QT + (ks * 4 + m) * 1024 + swbase);
                acc = MFMA(wa, ob, acc);
            }
            const int t = m * 16 + l15;
            if (t < 49) {
                const int tr = t / 7, tc = t - tr * 7;
                int r = wi7 + tr + 3; if (r >= 224) r -= 224;
                int c = wj7 + tc + 3; if (c >= 224) c -= 224;
                const float4 bo = *(const float4*)(bout + nn * 16 + lg * 4);
                float4 res;
                res.x = acc[0] + bo.x; res.y = acc[1] + bo.y;
                res.z = acc[2] + bo.z; res.w = acc[3] + bo.w;
                *(float4*)(out + ((size_t)((bb * 224 + r) * 224 + c)) * 96 + nn * 16 + lg * 4) = res;
            }
        }
    }
}

extern "C" void kernel_launch(void* const* d_in, const int* in_sizes, int n_in,
                              void* d_out, int out_size, void* d_ws, size_t ws_size,
                              hipStream_t stream) {
    const float* x          = (const float*)d_in[0];
    const float* w_qkv      = (const float*)d_in[1];
    const float* b_qkv      = (const float*)d_in[2];
    const float* w_out      = (const float*)d_in[3];
    const float* b_out      = (const float*)d_in[4];
    const float* bias_table = (const float*)d_in[5];
    const int*   rel_index  = (const int*)d_in[6];
    float* outp = (float*)d_out;

    // d_ws: wq16[27648]u16 | wo16[9216]u16 | bmat[3*64*64]f32  (122880 B total)
    u16* wq16 = (u16*)d_ws;
    u16* wo16 = wq16 + 27648;
    float* bmat = (float*)((char*)d_ws + 73728);

    prep_kernel<<<dim3(192), dim3(256), 0, stream>>>(
        w_qkv, w_out, bias_table, rel_index, wq16, wo16, bmat);
    swin_kernel<<<dim3(8192), dim3(256), 0, stream>>>(
        x, wq16, wo16, b_qkv, b_out, bmat, outp);
}